// Round 1
// baseline (993.117 us; speedup 1.0000x reference)
//
#include <hip/hip_runtime.h>
#include <hip/hip_bf16.h>

#define KTOP 8
#define NEXP 64
#define NFLAT 8192
#define CAP 256
#define HDIM 1024
#define IDIM 512

// ---------------- routing: stable counting sort by expert ----------------
// One block, 1024 threads. 64 chunks of 128 items.
__global__ __launch_bounds__(1024) void moe_routing(const int* __restrict__ ids,
        int* __restrict__ counts_g, int* __restrict__ row_map,
        float* __restrict__ sort_out)
{
    __shared__ int cnt[64][64];     // [chunk][expert]
    __shared__ int starts_s[64];
    const int tid = threadIdx.x;
    for (int i = tid; i < 64 * 64; i += 1024) ((int*)cnt)[i] = 0;
    __syncthreads();
    {   // histogram: thread t owns items [t*8, t*8+8) (always within one chunk)
        const int base = tid * 8;
        const int c = base >> 7;
        #pragma unroll
        for (int k = 0; k < 8; ++k) atomicAdd(&cnt[c][ids[base + k]], 1);
    }
    __syncthreads();
    if (tid < 64) {                 // per-expert totals
        int tot = 0;
        for (int c = 0; c < 64; ++c) tot += cnt[c][tid];
        counts_g[tid] = tot;
        starts_s[tid] = tot;
    }
    __syncthreads();
    if (tid == 0) {                 // exclusive prefix over experts (64 iters, trivial)
        int run = 0;
        for (int e = 0; e < 64; ++e) { int t = starts_s[e]; starts_s[e] = run; run += t; }
    }
    __syncthreads();
    if (tid < 64) {                 // cnt[c][e] -> absolute base offset of chunk c in expert e
        int run = starts_s[tid];
        for (int c = 0; c < 64; ++c) { int t = cnt[c][tid]; cnt[c][tid] = run; run += t; }
    }
    __syncthreads();
    if (tid < 64) {                 // stable rank assignment: thread = chunk, serial in-order
        const int c = tid;
        for (int k = 0; k < 128; ++k) {
            const int i = c * 128 + k;
            const int e = ids[i];
            const int p = cnt[c][e]++;                 // absolute sorted position
            row_map[e * CAP + (p - starts_s[e])] = i;  // slot within expert -> flat idx
            sort_out[p] = (float)i;                    // sort_idx output
        }
    }
}

// ---------------- GEMM1: gather(hidden) x w13 -> SwiGLU -> inter ----------------
// tile: 64 rows x 64 inter-cols (= 128 w13 cols: gate j0.. and up 512+j0..), BK=16
__global__ __launch_bounds__(256) void moe_gemm1(const float* __restrict__ hidden,
        const float* __restrict__ w13, const int* __restrict__ counts,
        const int* __restrict__ row_map, float* __restrict__ inter)
{
    const int e  = blockIdx.x >> 2;       // CAP/64 = 4 mtiles
    const int mt = blockIdx.x & 3;
    const int cnt = counts[e];
    if (mt * 64 >= cnt) return;           // ragged early-exit
    const int j0 = blockIdx.y * 64;

    __shared__ float As[16][68];          // [k][m], stride 68 floats = 16B-aligned rows
    __shared__ float Bs[16][128];         // cols 0..63 gate, 64..127 up

    const int tid = threadIdx.x;
    const int tm = tid >> 4;              // 0..15
    const int tn = tid & 15;              // 0..15

    const float* __restrict__ w13e = w13 + (size_t)e * HDIM * (2 * IDIM);

    int tokq[4];                          // gather tokens for the 4 A-rows this thread loads
    #pragma unroll
    for (int q = 0; q < 4; ++q) {
        const int row = mt * 64 + (tid >> 4) + q * 16;
        const int idx = (row < cnt) ? row_map[e * CAP + row] : 0;  // clamp OOB to row 0 (never read back)
        tokq[q] = idx >> 3;               // /KTOP
    }

    float gacc[4][4] = {{0.f}};
    float uacc[4][4] = {{0.f}};

    for (int k0 = 0; k0 < HDIM; k0 += 16) {
        #pragma unroll
        for (int q = 0; q < 4; ++q) {     // A: 64x16, transposed into LDS
            const int r  = (tid >> 4) + q * 16;
            const int kk = tid & 15;
            As[kk][r] = hidden[(size_t)tokq[q] * HDIM + k0 + kk];
        }
        {                                  // B: 16x128 (gate | up), coalesced along cols
            const int c = tid & 127;
            const int col = (c < 64) ? (j0 + c) : (IDIM + j0 + (c - 64));
            #pragma unroll
            for (int q = 0; q < 8; ++q) {
                const int kk = (tid >> 7) + q * 2;
                Bs[kk][c] = w13e[(size_t)(k0 + kk) * (2 * IDIM) + col];
            }
        }
        __syncthreads();
        #pragma unroll
        for (int kk = 0; kk < 16; ++kk) {
            float a[4], bg[4], bu[4];
            #pragma unroll
            for (int x = 0; x < 4; ++x) a[x]  = As[kk][tm * 4 + x];
            #pragma unroll
            for (int y = 0; y < 4; ++y) bg[y] = Bs[kk][tn * 4 + y];
            #pragma unroll
            for (int y = 0; y < 4; ++y) bu[y] = Bs[kk][64 + tn * 4 + y];
            #pragma unroll
            for (int x = 0; x < 4; ++x)
                #pragma unroll
                for (int y = 0; y < 4; ++y) {
                    gacc[x][y] = fmaf(a[x], bg[y], gacc[x][y]);
                    uacc[x][y] = fmaf(a[x], bu[y], uacc[x][y]);
                }
        }
        __syncthreads();
    }

    // epilogue: SwiGLU, write all tile rows (garbage rows beyond cnt are finite, never read)
    float* __restrict__ intere = inter + (size_t)e * CAP * IDIM;
    #pragma unroll
    for (int x = 0; x < 4; ++x) {
        const int row = mt * 64 + tm * 4 + x;
        float* dst = intere + (size_t)row * IDIM + j0 + tn * 4;
        #pragma unroll
        for (int y = 0; y < 4; ++y) {
            const float g = gacc[x][y];
            const float u = uacc[x][y];
            dst[y] = (g / (1.f + expf(-g))) * u;   // silu(g)*u
        }
    }
}

// ---------------- GEMM2: inter x w2 -> scatter to expanded_out ----------------
__global__ __launch_bounds__(256) void moe_gemm2(const float* __restrict__ inter,
        const float* __restrict__ w2, const int* __restrict__ counts,
        const int* __restrict__ row_map, float* __restrict__ expanded)
{
    const int e  = blockIdx.x >> 2;
    const int mt = blockIdx.x & 3;
    const int cnt = counts[e];
    if (mt * 64 >= cnt) return;
    const int j0 = blockIdx.y * 64;

    __shared__ float As[16][68];
    __shared__ float Bs[16][64];

    const int tid = threadIdx.x;
    const int tm = tid >> 4;
    const int tn = tid & 15;

    const float* __restrict__ intere = inter + (size_t)e * CAP * IDIM;
    const float* __restrict__ w2e = w2 + (size_t)e * IDIM * HDIM;

    float acc[4][4] = {{0.f}};

    for (int k0 = 0; k0 < IDIM; k0 += 16) {
        #pragma unroll
        for (int q = 0; q < 4; ++q) {
            const int r  = (tid >> 4) + q * 16;
            const int kk = tid & 15;
            As[kk][r] = intere[(size_t)(mt * 64 + r) * IDIM + k0 + kk];
        }
        #pragma unroll
        for (int q = 0; q < 4; ++q) {
            const int c  = tid & 63;
            const int kk = (tid >> 6) + q * 4;
            Bs[kk][c] = w2e[(size_t)(k0 + kk) * HDIM + j0 + c];
        }
        __syncthreads();
        #pragma unroll
        for (int kk = 0; kk < 16; ++kk) {
            float a[4], b[4];
            #pragma unroll
            for (int x = 0; x < 4; ++x) a[x] = As[kk][tm * 4 + x];
            #pragma unroll
            for (int y = 0; y < 4; ++y) b[y] = Bs[kk][tn * 4 + y];
            #pragma unroll
            for (int x = 0; x < 4; ++x)
                #pragma unroll
                for (int y = 0; y < 4; ++y)
                    acc[x][y] = fmaf(a[x], b[y], acc[x][y]);
        }
        __syncthreads();
    }

    #pragma unroll
    for (int x = 0; x < 4; ++x) {
        const int row = mt * 64 + tm * 4 + x;
        if (row < cnt) {
            const int i = row_map[e * CAP + row];
            float* dst = expanded + (size_t)i * HDIM + j0 + tn * 4;
            #pragma unroll
            for (int y = 0; y < 4; ++y) dst[y] = acc[x][y];
        }
    }
}

// ---------------- passthrough copies ----------------
__global__ void copy_vec4(const float4* __restrict__ in, float4* __restrict__ out, int n4)
{
    int i = blockIdx.x * blockDim.x + threadIdx.x;
    const int stride = gridDim.x * blockDim.x;
    for (; i < n4; i += stride) out[i] = in[i];
}

extern "C" void kernel_launch(void* const* d_in, const int* in_sizes, int n_in,
                              void* d_out, int out_size, void* d_ws, size_t ws_size,
                              hipStream_t stream)
{
    const float* hidden   = (const float*)d_in[0];   // [1024,1024]
    const float* topk_w   = (const float*)d_in[1];   // [1024,8]
    const int*   topk_ids = (const int*)  d_in[2];   // [1024,8]
    const float* w13      = (const float*)d_in[3];   // [64,1024,1024]
    const float* w2       = (const float*)d_in[4];   // [64,512,1024]

    float* out = (float*)d_out;
    float* out_hidden   = out;                               // 1,048,576
    float* out_expanded = out + 1048576;                     // 8,388,608
    float* out_tkw      = out + 1048576 + 8388608;           // 8,192
    float* out_sort     = out_tkw + 8192;                    // 8,192

    char* ws = (char*)d_ws;
    int*   counts  = (int*)ws;                  // 64 ints
    int*   row_map = (int*)(ws + 256);          // 16384 ints
    float* inter   = (float*)(ws + (1 << 17));  // 64*256*512 floats = 33.5 MB

    moe_routing<<<1, 1024, 0, stream>>>(topk_ids, counts, row_map, out_sort);
    moe_gemm1<<<dim3(NEXP * (CAP / 64), IDIM / 64), 256, 0, stream>>>(
        hidden, w13, counts, row_map, inter);
    moe_gemm2<<<dim3(NEXP * (CAP / 64), HDIM / 64), 256, 0, stream>>>(
        inter, w2, counts, row_map, out_expanded);
    copy_vec4<<<512, 256, 0, stream>>>((const float4*)hidden, (float4*)out_hidden, 1048576 / 4);
    copy_vec4<<<8, 256, 0, stream>>>((const float4*)topk_w, (float4*)out_tkw, 8192 / 4);
}